// Round 9
// baseline (109.052 us; speedup 1.0000x reference)
//
#include <hip/hip_runtime.h>
#include <cstdint>

#define MARGIN_F 0.2f

typedef __attribute__((ext_vector_type(8))) short sv8;   // 8 x bf16 (4 VGPRs)
typedef __attribute__((ext_vector_type(4))) float fv4;   // MFMA accumulator

// ---- round-to-nearest-even fp32 -> bf16 (bit pattern) ----
__device__ __forceinline__ unsigned short f2bf(float x) {
    unsigned u = __float_as_uint(x);
    unsigned r = (u + 0x7fffu + ((u >> 16) & 1u)) >> 16;
    return (unsigned short)r;
}

// ---- async global->LDS, 16B per lane (dest = wave-uniform base + lane*16) ----
__device__ __forceinline__ void gload16(const void* g, void* l) {
    __builtin_amdgcn_global_load_lds(
        (const __attribute__((address_space(1))) unsigned*)g,
        (__attribute__((address_space(3))) unsigned*)l,
        16, 0, 0);
}

// =====================================================================
// prep: norms, d_pos (fp32 exact) + bf16 conversion of e1,e2
// =====================================================================
__global__ __launch_bounds__(128) void prep_kernel(
    const float* __restrict__ e1, const float* __restrict__ e2,
    unsigned short* __restrict__ e1b, unsigned short* __restrict__ e2b,
    float* __restrict__ n1, float* __restrict__ n2, float* __restrict__ dpos)
{
    const int row = blockIdx.x;
    const int t = threadIdx.x;
    const float4 a = reinterpret_cast<const float4*>(e1 + (size_t)row * 512)[t];
    const float4 b = reinterpret_cast<const float4*>(e2 + (size_t)row * 512)[t];

    ushort4 pa, pb;
    pa.x = f2bf(a.x); pa.y = f2bf(a.y); pa.z = f2bf(a.z); pa.w = f2bf(a.w);
    pb.x = f2bf(b.x); pb.y = f2bf(b.y); pb.z = f2bf(b.z); pb.w = f2bf(b.w);
    reinterpret_cast<ushort4*>(e1b + (size_t)row * 512)[t] = pa;
    reinterpret_cast<ushort4*>(e2b + (size_t)row * 512)[t] = pb;

    float s1 = a.x*a.x + a.y*a.y + a.z*a.z + a.w*a.w;
    float s2 = b.x*b.x + b.y*b.y + b.z*b.z + b.w*b.w;
    float dx = a.x-b.x, dy = a.y-b.y, dz = a.z-b.z, dw = a.w-b.w;
    float sp = dx*dx + dy*dy + dz*dz + dw*dw;

    #pragma unroll
    for (int o = 32; o; o >>= 1) {
        s1 += __shfl_down(s1, o);
        s2 += __shfl_down(s2, o);
        sp += __shfl_down(sp, o);
    }
    __shared__ float r1[2], r2[2], rp[2];
    if ((t & 63) == 0) { int wv = t >> 6; r1[wv] = s1; r2[wv] = s2; rp[wv] = sp; }
    __syncthreads();
    if (t == 0) {
        n1[row] = r1[0] + r1[1];
        n2[row] = r2[0] + r2[1];
        dpos[row] = sqrtf(rp[0] + rp[1]);
    }
}

// =====================================================================
// main: m201-template 8-phase 256x256 tiles, BK=64, 8 waves (2Mx4N),
// half-tile(16KB)-granular double-buffered staging with counted vmcnt.
// Flavors: bid<256: G12 full 16x16; then G11 triangle(136); G22 (136).
// Per K-tile, 4 phases:
//  q0: read a[0..7](kh0)+b01(kh0)  -> MFMA m0-7 x n0-1 (kh0)
//  q1: read b23(kh0)               -> MFMA m0-7 x n2-3 (kh0)
//  q2: read a[0..7](kh1)+b01(kh1)  -> MFMA m0-7 x n0-1 (kh1)
//  q3: read b23(kh1)               -> MFMA m0-7 x n2-3 (kh1)
// Stage stream: half-index hidx = g+4 staged at phase g (halves:
// tile X = hidx>>2, part = hidx&3 in {A0,A1,B0,B1}); slot-safe since a
// slot's overwrite is >=1 barrier after its last read. vmcnt(2) at every
// q3 phase (g%4==0, g<=24), vmcnt(0) at g==28 => tile landed before use.
// =====================================================================
__global__ __launch_bounds__(512, 2) void triplet_main(
    const unsigned short* __restrict__ e1b, const unsigned short* __restrict__ e2b,
    const float* __restrict__ n1, const float* __restrict__ n2,
    const float* __restrict__ dpos,
    float* __restrict__ total, unsigned* __restrict__ count)
{
    __shared__ char lds[131072];       // 2 x {A0,A1,B0,B1} x 16KB
    __shared__ float scRN[256], scRD[256], scCN[256], scCD[256];
    __shared__ float ltp[8];
    __shared__ unsigned lcp[8];

    // ---- XCD-chunked bijective swizzle (528 = 8 * 66) ----
    const int bid0 = blockIdx.x;
    const int bid  = (bid0 & 7) * 66 + (bid0 >> 3);

    // ---- flavor decode ----
    int bi, bj, flavor;                 // 0=G12 1=G11 2=G22
    if (bid < 256) { flavor = 0; bi = bid >> 4; bj = bid & 15; }
    else {
        int b = bid - 256; flavor = 1;
        if (b >= 136) { b -= 136; flavor = 2; }
        int r = 0;
        while (b >= 16 - r) { b -= 16 - r; ++r; }
        bi = r; bj = r + b;
    }
    const int i0 = bi << 8, j0 = bj << 8;
    const char* Xc = (const char*)((flavor == 2) ? e2b : e1b);   // i-side rows
    const char* Yc = (const char*)((flavor == 1) ? e1b : e2b);   // j-side rows
    const float* nR = (flavor == 2) ? n2 : n1;
    const float* nC = (flavor == 1) ? n1 : n2;
    const bool emitCol = (flavor == 0) || (i0 != j0);
    const bool needNeq = (i0 == j0);

    const int tid  = threadIdx.x;
    const int w    = tid >> 6;
    const int lane = tid & 63;
    const int l15  = lane & 15;
    const int l4   = lane >> 4;
    const int wr   = w >> 2;      // 0..1  (A half)
    const int wc   = w & 3;       // 0..3  (B: half wc>>1, sub wc&1)

    // ---- epilogue scalar preload (issued first; retires early) ----
    if (tid < 256)      { scRN[tid] = nR[i0 + tid]; scRD[tid] = dpos[i0 + tid]; }
    else { const int t = tid - 256; scCN[t] = nC[j0 + t]; scCD[t] = dpos[j0 + t]; }

    // ---- staging offsets: one half-tile = 128 rows x 128B = 2 gloads/thread --
    int off2[2];
    #pragma unroll
    for (int c = 0; c < 2; ++c) {
        const int chunk = tid + (c << 9);            // 0..1023
        const int row   = chunk >> 3;                // 0..127
        const int slot  = (chunk & 7) << 4;
        off2[c] = row * 1024 + (slot ^ ((row & 7) << 4));   // pre-swizzled src
    }
    const char* Xc2 = Xc + (long)i0 * 1024;
    const char* Yc2 = Yc + (long)j0 * 1024;

#define STAGEH(HIDX) do {                                                    \
    const int X_    = (HIDX) >> 2;                                           \
    const int part_ = (HIDX) & 3;                                            \
    char* slot_ = lds + ((X_ & 1) << 16) + (part_ << 14) + (w << 10);        \
    const char* src_ = (part_ >= 2 ? Yc2 : Xc2)                              \
                     + ((long)(part_ & 1) << 17) + ((long)X_ << 7);          \
    gload16(src_ + off2[0], slot_);                                          \
    gload16(src_ + off2[1], slot_ + 8192);                                   \
} while (0)

    // ---- swizzled ds_read bases; +m(n)*2048 per 16 rows, ^64 for kh1 ----
    const int swz = (l15 & 7) << 4;
    const int rsl = (l4 << 4) ^ swz;
    const int aB  = (wr << 14) + l15 * 128 + rsl;
    const int bB  = 32768 + ((wc >> 1) << 14) + ((wc & 1) << 13) + l15 * 128 + rsl;

    fv4 acc[8][4];
    #pragma unroll
    for (int m = 0; m < 8; ++m)
        #pragma unroll
        for (int n = 0; n < 4; ++n) acc[m][n] = (fv4)0.0f;

    // ---- prologue: halves 0..4 (t0 complete + t1.A0); wait t0; barrier ----
    STAGEH(0); STAGEH(1); STAGEH(2); STAGEH(3); STAGEH(4);
    asm volatile("s_waitcnt vmcnt(2)" ::: "memory");
    asm volatile("s_barrier" ::: "memory");

    // ---- 32 phases: 8 K-tiles x 4 phases ----
    sv8 a[8];
    #pragma unroll
    for (int g = 1; g <= 32; ++g) {
        const int tile = (g - 1) >> 2;
        const int q    = (g - 1) & 3;
        const int pb   = (tile & 1) << 16;
        const int kh   = (q >> 1) << 6;

        sv8 bb0, bb1;
        if (q == 0 || q == 2) {
            #pragma unroll
            for (int m = 0; m < 8; ++m)
                a[m] = *(const sv8*)(lds + pb + ((aB + m * 2048) ^ kh));
            bb0 = *(const sv8*)(lds + pb + ((bB          ) ^ kh));
            bb1 = *(const sv8*)(lds + pb + ((bB + 1 * 2048) ^ kh));
        } else {
            bb0 = *(const sv8*)(lds + pb + ((bB + 2 * 2048) ^ kh));
            bb1 = *(const sv8*)(lds + pb + ((bB + 3 * 2048) ^ kh));
        }

        const int hidx = g + 4;
        if (hidx < 32) STAGEH(hidx);

        if ((g & 3) == 0) {
            if (g <= 24)      asm volatile("s_waitcnt vmcnt(2)" ::: "memory");
            else if (g == 28) asm volatile("s_waitcnt vmcnt(0)" ::: "memory");
        }
        asm volatile("s_barrier" ::: "memory");

        const int np = (q & 1) << 1;
        __builtin_amdgcn_s_setprio(1);
        #pragma unroll
        for (int m = 0; m < 8; ++m) {
            acc[m][np]     = __builtin_amdgcn_mfma_f32_16x16x32_bf16(a[m], bb0, acc[m][np],     0, 0, 0);
            acc[m][np + 1] = __builtin_amdgcn_mfma_f32_16x16x32_bf16(a[m], bb1, acc[m][np + 1], 0, 0, 0);
        }
        __builtin_amdgcn_s_setprio(0);
        asm volatile("s_barrier" ::: "memory");
    }
#undef STAGEH

    // ---- fused epilogue (sqrt-domain): C/D col=lane&15, row=(lane>>4)*4+rr --
    float    ltot = 0.0f;
    unsigned lcnt = 0;

    float cN_[4], cD_[4], cM_[4];
    #pragma unroll
    for (int n = 0; n < 4; ++n) {
        const int cl = (wc << 6) + (n << 4) + l15;
        cN_[n] = scCN[cl]; cD_[n] = scCD[cl]; cM_[n] = cD_[n] + MARGIN_F;
    }

    #pragma unroll
    for (int m = 0; m < 8; ++m) {
        #pragma unroll
        for (int rr = 0; rr < 4; ++rr) {
            const int rl = (wr << 7) + (m << 4) + (l4 << 2) + rr;
            const float rN = scRN[rl], rD = scRD[rl], rM = rD + MARGIN_F;
            #pragma unroll
            for (int n = 0; n < 4; ++n) {
                const int cl = (wc << 6) + (n << 4) + l15;
                const float s = sqrtf(fmaxf(fmaf(-2.0f, acc[m][n][rr], rN + cN_[n]), 0.0f));
                const bool neq = (!needNeq) || (rl != cl);
                bool c1 = neq && (rD < s);
                lcnt += c1; ltot += c1 ? fmaxf(rM - s, 0.0f) : 0.0f;
                bool c2 = emitCol && neq && (cD_[n] < s);
                lcnt += c2; ltot += c2 ? fmaxf(cM_[n] - s, 0.0f) : 0.0f;
            }
        }
    }

    // ---- block reduction: wave shuffle -> LDS -> one atomic pair ----
    #pragma unroll
    for (int o = 32; o; o >>= 1) {
        ltot += __shfl_down(ltot, o);
        lcnt += __shfl_down(lcnt, o);
    }
    if (lane == 0) { ltp[w] = ltot; lcp[w] = lcnt; }
    __syncthreads();
    if (tid == 0) {
        float T = 0.0f; unsigned C = 0;
        #pragma unroll
        for (int x = 0; x < 8; ++x) { T += ltp[x]; C += lcp[x]; }
        atomicAdd(total, T);
        atomicAdd(count, C);
    }
}

__global__ void finalize_kernel(const float* __restrict__ total,
                                const unsigned* __restrict__ count,
                                float* __restrict__ out)
{
    out[0] = total[0] / fmaxf((float)count[0], 1.0f);
}

// =====================================================================
// Workspace layout (~8.6 MB):
//   [0,8)        : total (f32), count (u32)
//   [1024, ...)  : n1[4096], n2[4096], dpos[4096]  (f32)
//   [131072, ..) : e1b 4096x512 bf16 (4MB), then e2b (4MB)
// =====================================================================
extern "C" void kernel_launch(void* const* d_in, const int* in_sizes, int n_in,
                              void* d_out, int out_size, void* d_ws, size_t ws_size,
                              hipStream_t stream) {
    const float* e1 = (const float*)d_in[0];
    const float* e2 = (const float*)d_in[1];
    char* ws = (char*)d_ws;

    float*    total = (float*)ws;
    unsigned* count = (unsigned*)(ws + 4);
    float* n1   = (float*)(ws + 1024);
    float* n2   = n1 + 4096;
    float* dpos = n2 + 4096;
    unsigned short* e1b = (unsigned short*)(ws + (1 << 17));
    unsigned short* e2b = e1b + (size_t)4096 * 512;

    hipMemsetAsync(ws, 0, 64, stream);
    prep_kernel<<<4096, 128, 0, stream>>>(e1, e2, e1b, e2b, n1, n2, dpos);
    triplet_main<<<528, 512, 0, stream>>>(e1b, e2b, n1, n2, dpos, total, count);
    finalize_kernel<<<1, 1, 0, stream>>>(total, count, (float*)d_out);
}

// Round 10
// 95.055 us; speedup vs baseline: 1.1473x; 1.1473x over previous
//
#include <hip/hip_runtime.h>
#include <cstdint>

#define MARGIN_F 0.2f

typedef __attribute__((ext_vector_type(8))) short sv8;   // 8 x bf16 (4 VGPRs)
typedef __attribute__((ext_vector_type(4))) float fv4;   // MFMA accumulator

// ---- round-to-nearest-even fp32 -> bf16 (bit pattern) ----
__device__ __forceinline__ unsigned short f2bf(float x) {
    unsigned u = __float_as_uint(x);
    unsigned r = (u + 0x7fffu + ((u >> 16) & 1u)) >> 16;
    return (unsigned short)r;
}

// ---- async global->LDS, 16B per lane (dest = wave-uniform base + lane*16) ----
__device__ __forceinline__ void gload16(const void* g, void* l) {
    __builtin_amdgcn_global_load_lds(
        (const __attribute__((address_space(1))) unsigned*)g,
        (__attribute__((address_space(3))) unsigned*)l,
        16, 0, 0);
}

// =====================================================================
// prep: norms, d_pos (fp32 exact) + bf16 conversion of e1,e2
// =====================================================================
__global__ __launch_bounds__(128) void prep_kernel(
    const float* __restrict__ e1, const float* __restrict__ e2,
    unsigned short* __restrict__ e1b, unsigned short* __restrict__ e2b,
    float* __restrict__ n1, float* __restrict__ n2, float* __restrict__ dpos)
{
    const int row = blockIdx.x;
    const int t = threadIdx.x;
    const float4 a = reinterpret_cast<const float4*>(e1 + (size_t)row * 512)[t];
    const float4 b = reinterpret_cast<const float4*>(e2 + (size_t)row * 512)[t];

    ushort4 pa, pb;
    pa.x = f2bf(a.x); pa.y = f2bf(a.y); pa.z = f2bf(a.z); pa.w = f2bf(a.w);
    pb.x = f2bf(b.x); pb.y = f2bf(b.y); pb.z = f2bf(b.z); pb.w = f2bf(b.w);
    reinterpret_cast<ushort4*>(e1b + (size_t)row * 512)[t] = pa;
    reinterpret_cast<ushort4*>(e2b + (size_t)row * 512)[t] = pb;

    float s1 = a.x*a.x + a.y*a.y + a.z*a.z + a.w*a.w;
    float s2 = b.x*b.x + b.y*b.y + b.z*b.z + b.w*b.w;
    float dx = a.x-b.x, dy = a.y-b.y, dz = a.z-b.z, dw = a.w-b.w;
    float sp = dx*dx + dy*dy + dz*dz + dw*dw;

    #pragma unroll
    for (int o = 32; o; o >>= 1) {
        s1 += __shfl_down(s1, o);
        s2 += __shfl_down(s2, o);
        sp += __shfl_down(sp, o);
    }
    __shared__ float r1[2], r2[2], rp[2];
    if ((t & 63) == 0) { int wv = t >> 6; r1[wv] = s1; r2[wv] = s2; rp[wv] = sp; }
    __syncthreads();
    if (t == 0) {
        n1[row] = r1[0] + r1[1];
        n2[row] = r2[0] + r2[1];
        dpos[row] = sqrtf(rp[0] + rp[1]);
    }
}

// =====================================================================
// main: R8 kernel (m97-faithful schedule, 128x128 flavor tiles) with
// SUPERTILE-ORDERED tile enumeration for XCD-L2 locality:
//   G12 (bid<1024): 4x4 supertiles of 8x8 tiles, row-major; consecutive
//     bids = same supertile -> the CP's bid%8 XCD round-robin makes all
//     8 XCDs co-stream the SAME 1MB A-panel + 1MB B-panel (fits 4MB L2).
//   G11 (528): triangle in superblock order (diag blocks 36, offdiag 64).
//   G22 (528): same over e2.
// Inner loop/epilogue byte-identical to R8.
// grid: 2080 blocks x 256 threads (4 waves 2x2; wave region 64x64).
// =====================================================================
__global__ __launch_bounds__(256, 3) void triplet_main(
    const unsigned short* __restrict__ e1b, const unsigned short* __restrict__ e2b,
    const float* __restrict__ n1, const float* __restrict__ n2,
    const float* __restrict__ dpos,
    float* __restrict__ total, unsigned* __restrict__ count)
{
    __shared__ char buf[32768];        // A tile [0,16K) | B tile [16K,32K)
    __shared__ float scRN[128], scRD[128], scCN[128], scCD[128];
    __shared__ float lt[4];
    __shared__ unsigned lc[4];

    // ---- supertile-ordered decode (natural bid order; no chunk swizzle) ----
    const int bid = blockIdx.x;
    int bi, bj, flavor;                 // 0=G12 1=G11 2=G22
    if (bid < 1024) {
        flavor = 0;
        const int s  = bid >> 6;        // supertile 0..15 (4x4 grid of 8x8)
        const int q  = bid & 63;
        bi = ((s >> 2) << 3) + (q >> 3);
        bj = ((s & 3) << 3) + (q & 7);
    } else {
        int b = bid - 1024; flavor = 1;
        if (b >= 528) { b -= 528; flavor = 2; }
        // triangle superblocks over 4x4 supergrid: diag=36 tiles, offdiag=64
        int SR = 0, SC = 0, base = 0;
        {
            bool found = false;
            for (int sr_ = 0; sr_ < 4 && !found; ++sr_) {
                for (int sc_ = sr_; sc_ < 4; ++sc_) {
                    const int sz = (sr_ == sc_) ? 36 : 64;
                    if (b < base + sz) { SR = sr_; SC = sc_; found = true; break; }
                    base += sz;
                }
            }
        }
        const int q = b - base;
        if (SR == SC) {                 // bi<=bj within 8x8 diag superblock
            int r2_ = 0, rem = q;
            while (rem >= 8 - r2_) { rem -= 8 - r2_; ++r2_; }
            bi = (SR << 3) + r2_; bj = (SC << 3) + r2_ + rem;
        } else {
            bi = (SR << 3) + (q >> 3);
            bj = (SC << 3) + (q & 7);
        }
    }
    const int i0 = bi << 7, j0 = bj << 7;
    const char* Xc = (const char*)((flavor == 2) ? e2b : e1b);   // i-side rows
    const char* Yc = (const char*)((flavor == 1) ? e1b : e2b);   // j-side rows
    const float* nR = (flavor == 2) ? n2 : n1;
    const float* nC = (flavor == 1) ? n1 : n2;
    const bool emitCol = (flavor == 0) || (i0 != j0);
    const bool needNeq = (i0 == j0);

    const int tid  = threadIdx.x;
    const int w    = tid >> 6;
    const int lane = tid & 63;
    const int l15  = lane & 15;
    const int l4   = lane >> 4;
    const int wr   = w >> 1;      // 0..1
    const int wc   = w & 1;       // 0..1

    // ---- epilogue scalar preload (n-side, dpos per side) ----
    if (tid < 128)      { scRN[tid] = nR[i0 + tid]; scRD[tid] = dpos[i0 + tid]; }
    else { const int t = tid - 128; scCN[t] = nC[j0 + t]; scCD[t] = dpos[j0 + t]; }

    // ---- loop-invariant staging addresses (k enters as +128B/step) ----
    // chunk c: 0..3 -> A tile, 4..7 -> B tile; 8 gload16/thread/step (32KB)
    long srcA[4], srcB[4];
    #pragma unroll
    for (int c = 0; c < 4; ++c) {
        const int chA = tid + (c << 8);              // 0..1023
        const int rA  = chA >> 3;                    // 0..127
        srcA[c] = (long)(i0 + rA) * 1024 + (((chA & 7) << 4) ^ ((rA & 7) << 4));
        srcB[c] = (long)(j0 + rA) * 1024 + (((chA & 7) << 4) ^ ((rA & 7) << 4));
    }
    const char* baseA = Xc;
    const char* baseB = Yc;
    const int ldst = w << 10;                        // wave-uniform dest part

    // ---- loop-invariant swizzled ds_read bases; m/n step +2048, khalf ^64 --
    const int slot = (l4 << 4) ^ ((l15 & 7) << 4);
    const int aB = ((wr << 6) + l15) * 128 + slot;
    const int bB = 16384 + ((wc << 6) + l15) * 128 + slot;

    fv4 acc[4][4];
    #pragma unroll
    for (int m = 0; m < 4; ++m)
        #pragma unroll
        for (int n = 0; n < 4; ++n) acc[m][n] = (fv4)0.0f;

    // ---- m97 loop: stage -> sync -> compute(2 k-halves) -> sync ----
    for (int t = 0; t < 8; ++t) {
        const long kb = (long)t << 7;
        #pragma unroll
        for (int c = 0; c < 4; ++c) {
            gload16(baseA + srcA[c] + kb, buf + (c << 12) + ldst);
            gload16(baseB + srcB[c] + kb, buf + 16384 + (c << 12) + ldst);
        }
        __syncthreads();
        #pragma unroll
        for (int h = 0; h < 2; ++h) {
            const int H = h << 6;                    // ^0 / ^64
            sv8 a_[4], b_[4];
            #pragma unroll
            for (int m = 0; m < 4; ++m)
                a_[m] = *(const sv8*)(buf + ((aB + m * 2048) ^ H));
            #pragma unroll
            for (int n = 0; n < 4; ++n)
                b_[n] = *(const sv8*)(buf + ((bB + n * 2048) ^ H));
            #pragma unroll
            for (int m = 0; m < 4; ++m)
                #pragma unroll
                for (int n = 0; n < 4; ++n)
                    acc[m][n] = __builtin_amdgcn_mfma_f32_16x16x32_bf16(
                        a_[m], b_[n], acc[m][n], 0, 0, 0);
        }
        __syncthreads();
    }

    // ---- fused epilogue (sqrt-domain): C/D col=lane&15, row=(lane>>4)*4+rr --
    float    ltot = 0.0f;
    unsigned lcnt = 0;

    float cN_[4], cD_[4], cM_[4];
    #pragma unroll
    for (int n = 0; n < 4; ++n) {
        const int cl = (wc << 6) + (n << 4) + l15;
        cN_[n] = scCN[cl]; cD_[n] = scCD[cl]; cM_[n] = cD_[n] + MARGIN_F;
    }

    #pragma unroll
    for (int m = 0; m < 4; ++m) {
        #pragma unroll
        for (int rr = 0; rr < 4; ++rr) {
            const int rl = (wr << 6) + (m << 4) + (l4 << 2) + rr;
            const float rN = scRN[rl], rD = scRD[rl], rM = rD + MARGIN_F;
            #pragma unroll
            for (int n = 0; n < 4; ++n) {
                const int cl = (wc << 6) + (n << 4) + l15;
                const float s = sqrtf(fmaxf(fmaf(-2.0f, acc[m][n][rr], rN + cN_[n]), 0.0f));
                const bool neq = (!needNeq) || (rl != cl);
                bool c1 = neq && (rD < s);
                lcnt += c1; ltot += c1 ? fmaxf(rM - s, 0.0f) : 0.0f;
                bool c2 = emitCol && neq && (cD_[n] < s);
                lcnt += c2; ltot += c2 ? fmaxf(cM_[n] - s, 0.0f) : 0.0f;
            }
        }
    }

    // ---- block reduction: wave shuffle -> LDS -> one atomic pair ----
    #pragma unroll
    for (int o = 32; o; o >>= 1) {
        ltot += __shfl_down(ltot, o);
        lcnt += __shfl_down(lcnt, o);
    }
    if (lane == 0) { lt[w] = ltot; lc[w] = lcnt; }
    __syncthreads();
    if (tid == 0) {
        float T = 0.0f; unsigned C = 0;
        #pragma unroll
        for (int x = 0; x < 4; ++x) { T += lt[x]; C += lc[x]; }
        atomicAdd(total, T);
        atomicAdd(count, C);
    }
}

__global__ void finalize_kernel(const float* __restrict__ total,
                                const unsigned* __restrict__ count,
                                float* __restrict__ out)
{
    out[0] = total[0] / fmaxf((float)count[0], 1.0f);
}

// =====================================================================
// Workspace layout (~8.6 MB):
//   [0,8)        : total (f32), count (u32)
//   [1024, ...)  : n1[4096], n2[4096], dpos[4096]  (f32)
//   [131072, ..) : e1b 4096x512 bf16 (4MB), then e2b (4MB)
// =====================================================================
extern "C" void kernel_launch(void* const* d_in, const int* in_sizes, int n_in,
                              void* d_out, int out_size, void* d_ws, size_t ws_size,
                              hipStream_t stream) {
    const float* e1 = (const float*)d_in[0];
    const float* e2 = (const float*)d_in[1];
    char* ws = (char*)d_ws;

    float*    total = (float*)ws;
    unsigned* count = (unsigned*)(ws + 4);
    float* n1   = (float*)(ws + 1024);
    float* n2   = n1 + 4096;
    float* dpos = n2 + 4096;
    unsigned short* e1b = (unsigned short*)(ws + (1 << 17));
    unsigned short* e2b = e1b + (size_t)4096 * 512;

    hipMemsetAsync(ws, 0, 64, stream);
    prep_kernel<<<4096, 128, 0, stream>>>(e1, e2, e1b, e2b, n1, n2, dpos);
    triplet_main<<<2080, 256, 0, stream>>>(e1b, e2b, n1, n2, dpos, total, count);
    finalize_kernel<<<1, 1, 0, stream>>>(total, count, (float*)d_out);
}

// Round 11
// 93.507 us; speedup vs baseline: 1.1662x; 1.0166x over previous
//
#include <hip/hip_runtime.h>
#include <cstdint>

#define MARGIN_F 0.2f

typedef __attribute__((ext_vector_type(8))) short sv8;   // 8 x bf16 (4 VGPRs)
typedef __attribute__((ext_vector_type(4))) float fv4;   // MFMA accumulator

// ---- round-to-nearest-even fp32 -> bf16 (bit pattern) ----
__device__ __forceinline__ unsigned short f2bf(float x) {
    unsigned u = __float_as_uint(x);
    unsigned r = (u + 0x7fffu + ((u >> 16) & 1u)) >> 16;
    return (unsigned short)r;
}

// ---- async global->LDS, 16B per lane (dest = wave-uniform base + lane*16) ----
__device__ __forceinline__ void gload16(const void* g, void* l) {
    __builtin_amdgcn_global_load_lds(
        (const __attribute__((address_space(1))) unsigned*)g,
        (__attribute__((address_space(3))) unsigned*)l,
        16, 0, 0);
}

// =====================================================================
// prep: norms, d_pos (fp32 exact) + bf16 conversion of e1,e2
// =====================================================================
__global__ __launch_bounds__(128) void prep_kernel(
    const float* __restrict__ e1, const float* __restrict__ e2,
    unsigned short* __restrict__ e1b, unsigned short* __restrict__ e2b,
    float* __restrict__ n1, float* __restrict__ n2, float* __restrict__ dpos)
{
    const int row = blockIdx.x;
    const int t = threadIdx.x;
    const float4 a = reinterpret_cast<const float4*>(e1 + (size_t)row * 512)[t];
    const float4 b = reinterpret_cast<const float4*>(e2 + (size_t)row * 512)[t];

    ushort4 pa, pb;
    pa.x = f2bf(a.x); pa.y = f2bf(a.y); pa.z = f2bf(a.z); pa.w = f2bf(a.w);
    pb.x = f2bf(b.x); pb.y = f2bf(b.y); pb.z = f2bf(b.z); pb.w = f2bf(b.w);
    reinterpret_cast<ushort4*>(e1b + (size_t)row * 512)[t] = pa;
    reinterpret_cast<ushort4*>(e2b + (size_t)row * 512)[t] = pb;

    float s1 = a.x*a.x + a.y*a.y + a.z*a.z + a.w*a.w;
    float s2 = b.x*b.x + b.y*b.y + b.z*b.z + b.w*b.w;
    float dx = a.x-b.x, dy = a.y-b.y, dz = a.z-b.z, dw = a.w-b.w;
    float sp = dx*dx + dy*dy + dz*dz + dw*dw;

    #pragma unroll
    for (int o = 32; o; o >>= 1) {
        s1 += __shfl_down(s1, o);
        s2 += __shfl_down(s2, o);
        sp += __shfl_down(sp, o);
    }
    __shared__ float r1[2], r2[2], rp[2];
    if ((t & 63) == 0) { int wv = t >> 6; r1[wv] = s1; r2[wv] = s2; rp[wv] = sp; }
    __syncthreads();
    if (t == 0) {
        n1[row] = r1[0] + r1[1];
        n2[row] = r2[0] + r2[1];
        dpos[row] = sqrtf(rp[0] + rp[1]);
    }
}

// =====================================================================
// main: R8 body (m97-faithful 128x128 tiles) with MULTI-TILE BLOCKS:
// each block = one i-panel x a run of up to 4 consecutive j-tiles.
//   bid <  256 : G12 (bi = bid>>3, j-run (bid&7)*4, 4 tiles)
//   bid <  400 : G11 triangle rows, runs of <=4 (144 blocks)
//   bid >= 400 : G22 triangle rows, runs of <=4 (144 blocks)
// Next tile's step-0 stage issues BEFORE current tile's epilogue ->
// stage latency hides under epilogue VALU. 4x fewer launches/reduces.
// grid: 544 blocks x 256 threads (4 waves 2x2; wave region 64x64).
// =====================================================================
__global__ __launch_bounds__(256, 3) void triplet_main(
    const unsigned short* __restrict__ e1b, const unsigned short* __restrict__ e2b,
    const float* __restrict__ n1, const float* __restrict__ n2,
    const float* __restrict__ dpos,
    float* __restrict__ total, unsigned* __restrict__ count)
{
    __shared__ char buf[32768];        // A tile [0,16K) | B tile [16K,32K)
    __shared__ float scRN[128], scRD[128], scCN[128], scCD[128];
    __shared__ float lt[4];
    __shared__ unsigned lc[4];

    // ---- decode: (flavor, bi, bjStart, ntiles) ----
    const int bid = blockIdx.x;
    int bi, bjStart, ntiles, flavor;    // 0=G12 1=G11 2=G22
    if (bid < 256) {
        flavor = 0; bi = bid >> 3; bjStart = (bid & 7) << 2; ntiles = 4;
    } else {
        int b = bid - 256; flavor = 1;
        if (b >= 144) { b -= 144; flavor = 2; }
        int r = 0;
        while (b >= ((35 - r) >> 2)) { b -= (35 - r) >> 2; ++r; }
        bi = r; bjStart = r + (b << 2);
        ntiles = 32 - bjStart; if (ntiles > 4) ntiles = 4;
    }
    const int i0 = bi << 7;
    const char* Xc = (const char*)((flavor == 2) ? e2b : e1b);   // i-side rows
    const char* Yc = (const char*)((flavor == 1) ? e1b : e2b);   // j-side rows
    const float* nR = (flavor == 2) ? n2 : n1;
    const float* nC = (flavor == 1) ? n1 : n2;

    const int tid  = threadIdx.x;
    const int w    = tid >> 6;
    const int lane = tid & 63;
    const int l15  = lane & 15;
    const int l4   = lane >> 4;
    const int wr   = w >> 1;      // 0..1
    const int wc   = w & 1;       // 0..1

    // ---- loop-invariant staging addresses ----
    // chunk c: A at srcA[c]+kb; B at j0*1024 + srcBoff[c] + kb
    long srcA[4]; int srcBoff[4];
    #pragma unroll
    for (int c = 0; c < 4; ++c) {
        const int chA = tid + (c << 8);              // 0..1023
        const int rA  = chA >> 3;                    // 0..127
        const int swz = (((chA & 7) << 4) ^ ((rA & 7) << 4));
        srcA[c]    = (long)(i0 + rA) * 1024 + swz;
        srcBoff[c] = rA * 1024 + swz;
    }
    const int ldst = w << 10;                        // wave-uniform dest part

#define STAGE(T, J0) do {                                                    \
    const long kb_ = (long)(T) << 7;                                         \
    const long jb_ = (long)(J0) << 10;                                       \
    _Pragma("unroll")                                                        \
    for (int c = 0; c < 4; ++c) {                                            \
        gload16(Xc + srcA[c] + kb_, buf + (c << 12) + ldst);                 \
        gload16(Yc + jb_ + srcBoff[c] + kb_, buf + 16384 + (c << 12) + ldst);\
    }                                                                        \
} while (0)

    // ---- loop-invariant swizzled ds_read bases; m/n step +2048, khalf ^64 --
    const int slot = (l4 << 4) ^ ((l15 & 7) << 4);
    const int aB = ((wr << 6) + l15) * 128 + slot;
    const int bB = 16384 + ((wc << 6) + l15) * 128 + slot;

    // ---- initial scalars (i-side + first tile's j-side) + first stage ----
    const int j0first = bjStart << 7;
    if (tid < 128)      { scRN[tid] = nR[i0 + tid]; scRD[tid] = dpos[i0 + tid]; }
    else { const int t = tid - 128; scCN[t] = nC[j0first + t]; scCD[t] = dpos[j0first + t]; }
    STAGE(0, j0first);

    float    ltot = 0.0f;
    unsigned lcnt = 0;
    fv4 acc[4][4];

    for (int tt = 0; tt < ntiles; ++tt) {
        const int j0     = (bjStart + tt) << 7;
        const int j0next = j0 + 128;
        const bool last  = (tt + 1 >= ntiles);
        const bool needNeq = (i0 == j0);
        const bool emitCol = (flavor == 0) || (i0 != j0);

        #pragma unroll
        for (int m = 0; m < 4; ++m)
            #pragma unroll
            for (int n = 0; n < 4; ++n) acc[m][n] = (fv4)0.0f;

        // ---- K-loop: sync (stage landed) -> compute -> sync -> stage next --
        #pragma unroll 1
        for (int t = 0; t < 8; ++t) {
            __syncthreads();
            #pragma unroll
            for (int h = 0; h < 2; ++h) {
                const int H = h << 6;                    // ^0 / ^64
                sv8 a_[4], b_[4];
                #pragma unroll
                for (int m = 0; m < 4; ++m)
                    a_[m] = *(const sv8*)(buf + ((aB + m * 2048) ^ H));
                #pragma unroll
                for (int n = 0; n < 4; ++n)
                    b_[n] = *(const sv8*)(buf + ((bB + n * 2048) ^ H));
                #pragma unroll
                for (int m = 0; m < 4; ++m)
                    #pragma unroll
                    for (int n = 0; n < 4; ++n)
                        acc[m][n] = __builtin_amdgcn_mfma_f32_16x16x32_bf16(
                            a_[m], b_[n], acc[m][n], 0, 0, 0);
            }
            __syncthreads();
            if (t < 7)        STAGE(t + 1, j0);
            else if (!last)   STAGE(0, j0next);   // hides under epilogue
        }

        // ---- fused epilogue (sqrt-domain): col=lane&15, row=(lane>>4)*4+rr --
        float cN_[4], cD_[4], cM_[4];
        #pragma unroll
        for (int n = 0; n < 4; ++n) {
            const int cl = (wc << 6) + (n << 4) + l15;
            cN_[n] = scCN[cl]; cD_[n] = scCD[cl]; cM_[n] = cD_[n] + MARGIN_F;
        }
        #pragma unroll
        for (int m = 0; m < 4; ++m) {
            #pragma unroll
            for (int rr = 0; rr < 4; ++rr) {
                const int rl = (wr << 6) + (m << 4) + (l4 << 2) + rr;
                const float rN = scRN[rl], rD = scRD[rl], rM = rD + MARGIN_F;
                #pragma unroll
                for (int n = 0; n < 4; ++n) {
                    const int cl = (wc << 6) + (n << 4) + l15;
                    const float s = sqrtf(fmaxf(fmaf(-2.0f, acc[m][n][rr], rN + cN_[n]), 0.0f));
                    const bool neq = (!needNeq) || (rl != cl);
                    bool c1 = neq && (rD < s);
                    lcnt += c1; ltot += c1 ? fmaxf(rM - s, 0.0f) : 0.0f;
                    bool c2 = emitCol && neq && (cD_[n] < s);
                    lcnt += c2; ltot += c2 ? fmaxf(cM_[n] - s, 0.0f) : 0.0f;
                }
            }
        }

        // ---- swap in next tile's j-side scalars (behind barrier) ----
        if (!last) {
            __syncthreads();            // epilogue scalar reads complete
            if (tid >= 128) {
                const int t = tid - 128;
                scCN[t] = nC[j0next + t]; scCD[t] = dpos[j0next + t];
            }
            // next iteration's first __syncthreads publishes these writes
        }
    }

    // ---- block reduction: wave shuffle -> LDS -> one atomic pair ----
    #pragma unroll
    for (int o = 32; o; o >>= 1) {
        ltot += __shfl_down(ltot, o);
        lcnt += __shfl_down(lcnt, o);
    }
    __syncthreads();
    if (lane == 0) { lt[w] = ltot; lc[w] = lcnt; }
    __syncthreads();
    if (tid == 0) {
        float T = 0.0f; unsigned C = 0;
        #pragma unroll
        for (int x = 0; x < 4; ++x) { T += lt[x]; C += lc[x]; }
        atomicAdd(total, T);
        atomicAdd(count, C);
    }
#undef STAGE
}

__global__ void finalize_kernel(const float* __restrict__ total,
                                const unsigned* __restrict__ count,
                                float* __restrict__ out)
{
    out[0] = total[0] / fmaxf((float)count[0], 1.0f);
}

// =====================================================================
// Workspace layout (~8.6 MB):
//   [0,8)        : total (f32), count (u32)
//   [1024, ...)  : n1[4096], n2[4096], dpos[4096]  (f32)
//   [131072, ..) : e1b 4096x512 bf16 (4MB), then e2b (4MB)
// =====================================================================
extern "C" void kernel_launch(void* const* d_in, const int* in_sizes, int n_in,
                              void* d_out, int out_size, void* d_ws, size_t ws_size,
                              hipStream_t stream) {
    const float* e1 = (const float*)d_in[0];
    const float* e2 = (const float*)d_in[1];
    char* ws = (char*)d_ws;

    float*    total = (float*)ws;
    unsigned* count = (unsigned*)(ws + 4);
    float* n1   = (float*)(ws + 1024);
    float* n2   = n1 + 4096;
    float* dpos = n2 + 4096;
    unsigned short* e1b = (unsigned short*)(ws + (1 << 17));
    unsigned short* e2b = e1b + (size_t)4096 * 512;

    hipMemsetAsync(ws, 0, 64, stream);
    prep_kernel<<<4096, 128, 0, stream>>>(e1, e2, e1b, e2b, n1, n2, dpos);
    triplet_main<<<544, 256, 0, stream>>>(e1b, e2b, n1, n2, dpos, total, count);
    finalize_kernel<<<1, 1, 0, stream>>>(total, count, (float*)d_out);
}

// Round 12
// 89.572 us; speedup vs baseline: 1.2175x; 1.0439x over previous
//
#include <hip/hip_runtime.h>
#include <cstdint>

#define MARGIN_F 0.2f

typedef __attribute__((ext_vector_type(4))) float fv4;   // MFMA accumulator

// ---- async global->LDS, 16B per lane (dest = wave-uniform base + lane*16) ----
__device__ __forceinline__ void gload16(const void* g, void* l) {
    __builtin_amdgcn_global_load_lds(
        (const __attribute__((address_space(1))) unsigned*)g,
        (__attribute__((address_space(3))) unsigned*)l,
        16, 0, 0);
}

// =====================================================================
// prep: norms, d_pos (fp32 exact) + fp8 e4m3fn conversion of e1,e2
// grid: 4096 blocks x 128 threads (each thread: 4 floats of one row)
// =====================================================================
__global__ __launch_bounds__(128) void prep_kernel(
    const float* __restrict__ e1, const float* __restrict__ e2,
    unsigned* __restrict__ e1q, unsigned* __restrict__ e2q,   // 4 fp8 / uint
    float* __restrict__ n1, float* __restrict__ n2, float* __restrict__ dpos)
{
    const int row = blockIdx.x;
    const int t = threadIdx.x;
    const float4 a = reinterpret_cast<const float4*>(e1 + (size_t)row * 512)[t];
    const float4 b = reinterpret_cast<const float4*>(e2 + (size_t)row * 512)[t];

    // pack 4 floats -> 4 x e4m3fn (v_cvt_pk_fp8_f32, RNE, OCP on gfx950)
    int pa = __builtin_amdgcn_cvt_pk_fp8_f32(a.x, a.y, 0, false);
    pa     = __builtin_amdgcn_cvt_pk_fp8_f32(a.z, a.w, pa, true);
    int pb = __builtin_amdgcn_cvt_pk_fp8_f32(b.x, b.y, 0, false);
    pb     = __builtin_amdgcn_cvt_pk_fp8_f32(b.z, b.w, pb, true);
    e1q[row * 128 + t] = (unsigned)pa;
    e2q[row * 128 + t] = (unsigned)pb;

    float s1 = a.x*a.x + a.y*a.y + a.z*a.z + a.w*a.w;
    float s2 = b.x*b.x + b.y*b.y + b.z*b.z + b.w*b.w;
    float dx = a.x-b.x, dy = a.y-b.y, dz = a.z-b.z, dw = a.w-b.w;
    float sp = dx*dx + dy*dy + dz*dz + dw*dw;

    #pragma unroll
    for (int o = 32; o; o >>= 1) {
        s1 += __shfl_down(s1, o);
        s2 += __shfl_down(s2, o);
        sp += __shfl_down(sp, o);
    }
    __shared__ float r1[2], r2[2], rp[2];
    if ((t & 63) == 0) { int wv = t >> 6; r1[wv] = s1; r2[wv] = s2; rp[wv] = sp; }
    __syncthreads();
    if (t == 0) {
        n1[row] = r1[0] + r1[1];
        n2[row] = r2[0] + r2[1];
        dpos[row] = sqrtf(rp[0] + rp[1]);
    }
}

// =====================================================================
// main: R8 structure (m97-faithful schedule, 128x128 flavor tiles),
// fp8 e4m3 grams: LDS geometry identical (128 rows x 128B per panel),
// but one row-step now covers K=128 (4 steps total, 4 sub-K MFMA each).
//   bid <  1024 : G12 = e1 . e2^T, FULL 32x32 grid (D12 row + D21 col)
//   bid <  1552 : G11 triangle bi<=bj (row + sym col terms)
//   bid >= 1552 : G22 triangle
// grid: 2080 blocks x 256 threads (4 waves 2x2; wave region 64x64).
// =====================================================================
__global__ __launch_bounds__(256, 3) void triplet_main(
    const unsigned char* __restrict__ e1q, const unsigned char* __restrict__ e2q,
    const float* __restrict__ n1, const float* __restrict__ n2,
    const float* __restrict__ dpos,
    float* __restrict__ total, unsigned* __restrict__ count)
{
    __shared__ char buf[32768];        // A tile [0,16K) | B tile [16K,32K)
    __shared__ float scRN[128], scRD[128], scCN[128], scCD[128];
    __shared__ float lt[4];
    __shared__ unsigned lc[4];

    // ---- flavor decode (R8 order) ----
    const int bid = blockIdx.x;
    int bi, bj, flavor;                 // 0=G12 1=G11 2=G22
    if (bid < 1024) { flavor = 0; bi = bid >> 5; bj = bid & 31; }
    else {
        int b = bid - 1024; flavor = 1;
        if (b >= 528) { b -= 528; flavor = 2; }
        int r = (int)((65.0f - sqrtf(4225.0f - 8.0f * (float)b)) * 0.5f);
        while (32 * r - (r * (r - 1)) / 2 > b) --r;
        while (32 * (r + 1) - ((r + 1) * r) / 2 <= b) ++r;
        bi = r; bj = r + (b - (32 * r - (r * (r - 1)) / 2));
    }
    const int i0 = bi << 7, j0 = bj << 7;
    const char* Xc = (const char*)((flavor == 2) ? e2q : e1q);   // i-side rows
    const char* Yc = (const char*)((flavor == 1) ? e1q : e2q);   // j-side rows
    const float* nR = (flavor == 2) ? n2 : n1;
    const float* nC = (flavor == 1) ? n1 : n2;
    const bool emitCol = (flavor == 0) || (i0 != j0);
    const bool needNeq = (i0 == j0);

    const int tid  = threadIdx.x;
    const int w    = tid >> 6;
    const int lane = tid & 63;
    const int l15  = lane & 15;
    const int l4   = lane >> 4;
    const int wr   = w >> 1;      // 0..1
    const int wc   = w & 1;       // 0..1

    // ---- epilogue scalar preload ----
    if (tid < 128)      { scRN[tid] = nR[i0 + tid]; scRD[tid] = dpos[i0 + tid]; }
    else { const int t = tid - 128; scCN[t] = nC[j0 + t]; scCD[t] = dpos[j0 + t]; }

    // ---- staging addresses (fp8 row = 512B; K-step window = 128B) ----
    // chunk c 0..3 -> A panel, mirrored for B; 8 gload16/thread/step (32KB)
    long srcA[4];
    #pragma unroll
    for (int c = 0; c < 4; ++c) {
        const int chA = tid + (c << 8);              // 0..1023
        const int rA  = chA >> 3;                    // 0..127
        srcA[c] = (long)(i0 + rA) * 512 + (((chA & 7) << 4) ^ ((rA & 7) << 4));
    }
    const long jd = (long)(j0 - i0) * 512;           // B source delta (uniform)
    const int ldst = w << 10;                        // wave-uniform dest part

    // ---- precomputed swizzled ds_read addresses: adA/adB[m][kk] ----
    // logical: row r, sub-K kk -> bytes k=kk*32+l4*8 of the 128B window;
    // chunk = (kk<<1)|(l4>>1), stored at chunk^(r&7) (pre-swizzled source)
    int adA[4][4], adB[4][4];
    #pragma unroll
    for (int m = 0; m < 4; ++m) {
        const int rowA = (wr << 6) + (m << 4) + l15;
        const int rowB = (wc << 6) + (m << 4) + l15;
        #pragma unroll
        for (int kk = 0; kk < 4; ++kk) {
            const int ch = (kk << 1) | (l4 >> 1);
            adA[m][kk] = rowA * 128 + (((ch ^ (rowA & 7)) << 4) | ((l4 & 1) << 3));
            adB[m][kk] = 16384 + rowB * 128 + (((ch ^ (rowB & 7)) << 4) | ((l4 & 1) << 3));
        }
    }

    fv4 acc[4][4];
    #pragma unroll
    for (int m = 0; m < 4; ++m)
        #pragma unroll
        for (int n = 0; n < 4; ++n) acc[m][n] = (fv4)0.0f;

    // ---- m97 loop: stage -> sync -> compute(4 sub-K) -> sync; 4 steps ----
    for (int t = 0; t < 4; ++t) {
        const long kb = (long)t << 7;                // 128B K-window per step
        #pragma unroll
        for (int c = 0; c < 4; ++c) {
            gload16(Xc + srcA[c] + kb,      buf + (c << 12) + ldst);
            gload16(Yc + srcA[c] + jd + kb, buf + 16384 + (c << 12) + ldst);
        }
        __syncthreads();
        #pragma unroll
        for (int kk = 0; kk < 4; ++kk) {
            long a_[4], b_[4];
            #pragma unroll
            for (int m = 0; m < 4; ++m) a_[m] = *(const long*)(buf + adA[m][kk]);
            #pragma unroll
            for (int n = 0; n < 4; ++n) b_[n] = *(const long*)(buf + adB[n][kk]);
            #pragma unroll
            for (int m = 0; m < 4; ++m)
                #pragma unroll
                for (int n = 0; n < 4; ++n)
                    acc[m][n] = __builtin_amdgcn_mfma_f32_16x16x32_fp8_fp8(
                        a_[m], b_[n], acc[m][n], 0, 0, 0);
        }
        __syncthreads();
    }

    // ---- fused epilogue (sqrt-domain): C/D col=lane&15, row=(lane>>4)*4+rr --
    float    ltot = 0.0f;
    unsigned lcnt = 0;

    float cN_[4], cD_[4], cM_[4];
    #pragma unroll
    for (int n = 0; n < 4; ++n) {
        const int cl = (wc << 6) + (n << 4) + l15;
        cN_[n] = scCN[cl]; cD_[n] = scCD[cl]; cM_[n] = cD_[n] + MARGIN_F;
    }

    #pragma unroll
    for (int m = 0; m < 4; ++m) {
        #pragma unroll
        for (int rr = 0; rr < 4; ++rr) {
            const int rl = (wr << 6) + (m << 4) + (l4 << 2) + rr;
            const float rN = scRN[rl], rD = scRD[rl], rM = rD + MARGIN_F;
            #pragma unroll
            for (int n = 0; n < 4; ++n) {
                const int cl = (wc << 6) + (n << 4) + l15;
                const float s = sqrtf(fmaxf(fmaf(-2.0f, acc[m][n][rr], rN + cN_[n]), 0.0f));
                const bool neq = (!needNeq) || (rl != cl);
                bool c1 = neq && (rD < s);
                lcnt += c1; ltot += c1 ? fmaxf(rM - s, 0.0f) : 0.0f;
                bool c2 = emitCol && neq && (cD_[n] < s);
                lcnt += c2; ltot += c2 ? fmaxf(cM_[n] - s, 0.0f) : 0.0f;
            }
        }
    }

    // ---- block reduction: wave shuffle -> LDS -> one atomic pair ----
    #pragma unroll
    for (int o = 32; o; o >>= 1) {
        ltot += __shfl_down(ltot, o);
        lcnt += __shfl_down(lcnt, o);
    }
    if (lane == 0) { lt[w] = ltot; lc[w] = lcnt; }
    __syncthreads();
    if (tid == 0) {
        float T = 0.0f; unsigned C = 0;
        #pragma unroll
        for (int x = 0; x < 4; ++x) { T += lt[x]; C += lc[x]; }
        atomicAdd(total, T);
        atomicAdd(count, C);
    }
}

__global__ void finalize_kernel(const float* __restrict__ total,
                                const unsigned* __restrict__ count,
                                float* __restrict__ out)
{
    out[0] = total[0] / fmaxf((float)count[0], 1.0f);
}

// =====================================================================
// Workspace layout (~4.5 MB):
//   [0,8)        : total (f32), count (u32)
//   [1024, ...)  : n1[4096], n2[4096], dpos[4096]  (f32)
//   [131072, ..) : e1q 4096x512 fp8 (2MB), then e2q (2MB)
// =====================================================================
extern "C" void kernel_launch(void* const* d_in, const int* in_sizes, int n_in,
                              void* d_out, int out_size, void* d_ws, size_t ws_size,
                              hipStream_t stream) {
    const float* e1 = (const float*)d_in[0];
    const float* e2 = (const float*)d_in[1];
    char* ws = (char*)d_ws;

    float*    total = (float*)ws;
    unsigned* count = (unsigned*)(ws + 4);
    float* n1   = (float*)(ws + 1024);
    float* n2   = n1 + 4096;
    float* dpos = n2 + 4096;
    unsigned* e1q = (unsigned*)(ws + (1 << 17));
    unsigned* e2q = e1q + (size_t)4096 * 128;

    hipMemsetAsync(ws, 0, 64, stream);
    prep_kernel<<<4096, 128, 0, stream>>>(e1, e2, e1q, e2q, n1, n2, dpos);
    triplet_main<<<2080, 256, 0, stream>>>((const unsigned char*)e1q,
                                           (const unsigned char*)e2q,
                                           n1, n2, dpos, total, count);
    finalize_kernel<<<1, 1, 0, stream>>>(total, count, (float*)d_out);
}